// Round 9
// baseline (175.891 us; speedup 1.0000x reference)
//
#include <hip/hip_runtime.h>
#include <hip/hip_bf16.h>
#include <stdint.h>

typedef __attribute__((ext_vector_type(8))) short bf16x8;
typedef __attribute__((ext_vector_type(4))) float f32x4;

#define NPOS 256
#define NROW 512
#define NCH  256
#define PSTRIDE 262144   // bytes per position panel: 512 rows * 256 ch * 2B

// ---------------------------------------------------------------------------
// Kernel 1: repack fp32 [i][c][p] -> bf16 X[p][i][c]  (LDS tile transpose)
// FUSED SQ partials WITHOUT atomics: each (i,cb,pb) block computes
// SQP[cb][p0+pl][i] = sum over its 64 channels of round_bf16(x)^2.
// ---------------------------------------------------------------------------
__global__ __launch_bounds__(256) void k_repack(const float* __restrict__ src,
                                                const float* __restrict__ tgt,
                                                unsigned short* __restrict__ X,
                                                float* __restrict__ SQP) {
  __shared__ float tile[64 * 65];  // [c][p], +1 pad
  int bx = blockIdx.x;
  int i  = bx >> 4;
  int cb = (bx >> 2) & 3;
  int pb = bx & 3;
  int c0 = cb * 64, p0 = pb * 64;
  const float* base = (i < 256) ? (src + (size_t)i * 65536)
                                : (tgt + (size_t)(i - 256) * 65536);
  int t = threadIdx.x;
#pragma unroll
  for (int it = 0; it < 4; ++it) {
    int idx = it * 256 + t;
    int cl = idx >> 4, pq = idx & 15;                // float4 along p (coalesced)
    float4 v = *(const float4*)&base[(c0 + cl) * 256 + p0 + pq * 4];
    tile[cl * 65 + pq * 4 + 0] = v.x;
    tile[cl * 65 + pq * 4 + 1] = v.y;
    tile[cl * 65 + pq * 4 + 2] = v.z;
    tile[cl * 65 + pq * 4 + 3] = v.w;
  }
  __syncthreads();
#pragma unroll
  for (int it = 0; it < 2; ++it) {
    int idx = it * 256 + t;
    int pl = idx >> 3, c8 = idx & 7;                 // 8 threads per p-row
    unsigned rr[8];
    float part = 0.f;
#pragma unroll
    for (int j = 0; j < 8; ++j) {
      unsigned u = __float_as_uint(tile[(c8 * 8 + j) * 65 + pl]);
      rr[j] = (u + 0x7fffu + ((u >> 16) & 1u)) >> 16;        // RNE to bf16
      float fr = __uint_as_float(rr[j] << 16);               // square ROUNDED value
      part += fr * fr;
    }
    uint4 o = { rr[0] | (rr[1] << 16), rr[2] | (rr[3] << 16),
                rr[4] | (rr[5] << 16), rr[6] | (rr[7] << 16) };
    *(uint4*)&X[((size_t)(p0 + pl) * NROW + i) * NCH + c0 + c8 * 8] = o;
    // row-reduce over the 8 threads sharing pl (t bits 0..2)
    part += __shfl_xor(part, 1, 64);
    part += __shfl_xor(part, 2, 64);
    part += __shfl_xor(part, 4, 64);
    if (c8 == 0)
      SQP[(size_t)cb * (NPOS * NROW) + (size_t)(p0 + pl) * NROW + i] = part;
  }
}

// ---------------------------------------------------------------------------
// Kernel 2: fused Gram + RBF-sum epilogue, upper-triangle tiles only.
// r8 structure with LDS shrunk to EXACTLY 32768 B (As+Bs only) -> 5 blocks/CU
// (163840/32768) for cross-block latency hiding of the vmcnt(0) drains.
// SQ staged into dead As space AFTER the K-loop; per-WAVE partials go to
// global (no cross-wave LDS reduce).
// grid: 256 pos * 10 tiles(128x128) = 2560 blocks, 4 waves (2x2).
// ---------------------------------------------------------------------------
__device__ __forceinline__ int swz(int row, int byteoff) {
  return row * 128 + (byteoff ^ ((row & 7) << 4));
}

__global__ __launch_bounds__(256, 5) void k_mmd(const unsigned short* __restrict__ X,
                                                const float* __restrict__ SQP,
                                                float* __restrict__ part) {
  __shared__ unsigned short As[128 * 64];   // 16384 B
  __shared__ unsigned short Bs[128 * 64];   // 16384 B   -> total exactly 32768

  int bid = blockIdx.x;
  int bx = (bid & 7) * 320 + (bid >> 3);   // XCD swizzle (bijective: 2560 = 8*320)
  int p = bx / 10;
  int tileid = bx - p * 10;
  int it, jt;
  if (tileid < 4)      { it = 0; jt = tileid; }
  else if (tileid < 7) { it = 1; jt = tileid - 3; }
  else if (tileid < 9) { it = 2; jt = tileid - 5; }
  else                 { it = 3; jt = 3; }
  int i0 = it * 128, j0 = jt * 128;
  int t = threadIdx.x;
  int lane = t & 63, w = t >> 6;
  int wr = w >> 1, wc = w & 1;
  int l15 = lane & 15, lk = lane >> 4;
  bool diag = (it == jt);
  bool skipw = diag && (w == 2);           // mirror of wave (0,1)
  bool areuse = diag && (wr == wc);        // Gram: B-frags == A-frags

  const unsigned short* Xp = X + (size_t)p * (NROW * NCH);
  const char* XA = (const char*)Xp + (size_t)i0 * 512;   // 512 B per row
  const char* XB = (const char*)Xp + (size_t)j0 * 512;

  f32x4 zero = {0.f, 0.f, 0.f, 0.f};
  f32x4 acc[4][4];
#pragma unroll
  for (int m = 0; m < 4; ++m)
#pragma unroll
    for (int n = 0; n < 4; ++n) acc[m][n] = zero;

  // per-lane constant source swizzle: row&7 == lane>>3 for every issued chunk
  int lrow = lane >> 3;
  int coff = ((lane & 7) ^ lrow) * 16;

  for (int kk = 0; kk < 4; ++kk) {
#pragma unroll
    for (int s = 0; s < 4; ++s) {
      int rbase = w * 32 + s * 8;          // wave-uniform
      const char* ga = XA + (size_t)(rbase + lrow) * 512 + kk * 128 + coff;
      const char* gb = XB + (size_t)(rbase + lrow) * 512 + kk * 128 + coff;
      __builtin_amdgcn_global_load_lds(
          (const __attribute__((address_space(1))) void*)ga,
          (__attribute__((address_space(3))) void*)((char*)As + rbase * 128), 16, 0, 0);
      __builtin_amdgcn_global_load_lds(
          (const __attribute__((address_space(1))) void*)gb,
          (__attribute__((address_space(3))) void*)((char*)Bs + rbase * 128), 16, 0, 0);
    }
    __syncthreads();                       // drains vmcnt(0): staged data visible
    if (!skipw) {
#pragma unroll
      for (int ks = 0; ks < 2; ++ks) {
        bf16x8 a[4], b[4];
#pragma unroll
        for (int m = 0; m < 4; ++m)
          a[m] = *(const bf16x8*)((const char*)As + swz(wr * 64 + m * 16 + l15, ks * 64 + lk * 16));
        if (areuse) {
#pragma unroll
          for (int n = 0; n < 4; ++n) b[n] = a[n];
        } else {
#pragma unroll
          for (int n = 0; n < 4; ++n)
            b[n] = *(const bf16x8*)((const char*)Bs + swz(wc * 64 + n * 16 + l15, ks * 64 + lk * 16));
        }
#pragma unroll
        for (int m = 0; m < 4; ++m)
#pragma unroll
          for (int n = 0; n < 4; ++n)
            acc[m][n] = __builtin_amdgcn_mfma_f32_16x16x32_bf16(a[m], b[n], acc[m][n], 0, 0, 0);
      }
    }
    __syncthreads();
  }

  // K-loop done; As is dead -> stage SQ sums there (256 floats)
  float* SQsh = (float*)As;
  if (t < 128) {
    size_t q = (size_t)p * NROW + i0 + t;
    SQsh[t] = SQP[q] + SQP[q + 131072] + SQP[q + 262144] + SQP[q + 393216];
  } else if (t < 256) {
    size_t q = (size_t)p * NROW + j0 + (t - 128);
    SQsh[t] = SQP[q] + SQP[q + 131072] + SQP[q + 262144] + SQP[q + 393216];
  }
  __syncthreads();

  // epilogue: D = sqi + sqj - 2c ; K = sum_b exp(-D/b) via 1 exp2 + squarings
  float lsum = 0.f;
  if (!skipw) {
    const float c80 = 0.01803368801f;  // log2(e)/80
    float sqi[16], sqj[4];
#pragma unroll
    for (int m = 0; m < 4; ++m)
#pragma unroll
      for (int r = 0; r < 4; ++r) sqi[m * 4 + r] = SQsh[wr * 64 + m * 16 + lk * 4 + r];
#pragma unroll
    for (int n = 0; n < 4; ++n) sqj[n] = SQsh[128 + wc * 64 + n * 16 + l15];

    bool sdiag = diag && (wr == wc);
#pragma unroll
    for (int m = 0; m < 4; ++m) {
#pragma unroll
      for (int n = 0; n < 4; ++n) {
#pragma unroll
        for (int r = 0; r < 4; ++r) {
          float cv = acc[m][n][r];
          float D = sqi[m * 4 + r] + sqj[n] - 2.f * cv;
          float e80 = exp2f(-c80 * D);     // exp(-D/80)
          float e40 = e80 * e80;
          float e20 = e40 * e40;
          float e10 = e20 * e20;
          float e5  = e10 * e10;
          float e2  = e5 * e5 * e10;       // exp(-D/2)
          float K = (e80 + e40) + (e20 + e10) + (e5 + e2);
          if (sdiag && m == n) {
            if (lk * 4 + r == l15) K = 6.0f;   // exact diagonal: D==0 -> K=6
          }
          lsum += K;
        }
      }
    }
    if (diag && w == 1) lsum *= 2.0f;      // stands in for skipped mirror wave
  }
  // per-wave partial reduce; ALL waves write their slot (skipw writes 0)
#pragma unroll
  for (int off = 32; off; off >>= 1) lsum += __shfl_down(lsum, off, 64);
  if (lane == 0) {
    float sgn = ((it < 2) == (jt < 2)) ? 1.0f : -1.0f;
    float tw  = diag ? 1.0f : 2.0f;        // off-diag tiles count twice (symmetry)
    part[bx * 4 + w] = sgn * tw * lsum;
  }
}

// ---------------------------------------------------------------------------
// Kernel 3: deterministic final reduce of 10240 per-wave partials -> mean
// ---------------------------------------------------------------------------
__global__ __launch_bounds__(256) void k_reduce(const float* __restrict__ part,
                                                float* __restrict__ out) {
  __shared__ float wsum[4];
  int t = threadIdx.x;
  float s = 0.f;
#pragma unroll
  for (int i = 0; i < 40; ++i) s += part[i * 256 + t];
#pragma unroll
  for (int off = 32; off; off >>= 1) s += __shfl_down(s, off, 64);
  int lane = t & 63, w = t >> 6;
  if (lane == 0) wsum[w] = s;
  __syncthreads();
  if (t == 0) out[0] = (wsum[0] + wsum[1] + wsum[2] + wsum[3]) * (1.0f / 16777216.0f);
}

extern "C" void kernel_launch(void* const* d_in, const int* in_sizes, int n_in,
                              void* d_out, int out_size, void* d_ws, size_t ws_size,
                              hipStream_t stream) {
  (void)in_sizes; (void)n_in; (void)out_size; (void)ws_size;
  const float* src = (const float*)d_in[0];
  const float* tgt = (const float*)d_in[1];
  char* ws = (char*)d_ws;
  unsigned short* X = (unsigned short*)ws;                    // 67,108,864 B
  float* SQP  = (float*)(ws + 67108864);                      //  2,097,152 B (4 partials)
  float* PART = (float*)(ws + 67108864 + 2097152);            //     40,960 B

  hipLaunchKernelGGL(k_repack, dim3(8192), dim3(256), 0, stream, src, tgt, X, SQP);
  hipLaunchKernelGGL(k_mmd,    dim3(2560), dim3(256), 0, stream, X, SQP, PART);
  hipLaunchKernelGGL(k_reduce, dim3(1),    dim3(256), 0, stream, PART, (float*)d_out);
}

// Round 10
// 81.793 us; speedup vs baseline: 2.1504x; 2.1504x over previous
//
#include <hip/hip_runtime.h>
#include <hip/hip_bf16.h>
#include <stdint.h>

typedef __attribute__((ext_vector_type(8))) short bf16x8;
typedef __attribute__((ext_vector_type(4))) float f32x4;

#define NPOS 256
#define NROW 512
#define NCH  256
#define PSTRIDE 262144   // bytes per position panel: 512 rows * 256 ch * 2B

// ---------------------------------------------------------------------------
// Kernel 1: repack fp32 [i][c][p] -> bf16 X[p][i][c]  (LDS tile transpose)
// FUSED SQ partials WITHOUT atomics: each (i,cb,pb) block computes
// SQP[cb][p0+pl][i] = sum over its 64 channels of round_bf16(x)^2.
// ---------------------------------------------------------------------------
__global__ __launch_bounds__(256) void k_repack(const float* __restrict__ src,
                                                const float* __restrict__ tgt,
                                                unsigned short* __restrict__ X,
                                                float* __restrict__ SQP) {
  __shared__ float tile[64 * 65];  // [c][p], +1 pad
  int bx = blockIdx.x;
  int i  = bx >> 4;
  int cb = (bx >> 2) & 3;
  int pb = bx & 3;
  int c0 = cb * 64, p0 = pb * 64;
  const float* base = (i < 256) ? (src + (size_t)i * 65536)
                                : (tgt + (size_t)(i - 256) * 65536);
  int t = threadIdx.x;
#pragma unroll
  for (int it = 0; it < 4; ++it) {
    int idx = it * 256 + t;
    int cl = idx >> 4, pq = idx & 15;                // float4 along p (coalesced)
    float4 v = *(const float4*)&base[(c0 + cl) * 256 + p0 + pq * 4];
    tile[cl * 65 + pq * 4 + 0] = v.x;
    tile[cl * 65 + pq * 4 + 1] = v.y;
    tile[cl * 65 + pq * 4 + 2] = v.z;
    tile[cl * 65 + pq * 4 + 3] = v.w;
  }
  __syncthreads();
#pragma unroll
  for (int it = 0; it < 2; ++it) {
    int idx = it * 256 + t;
    int pl = idx >> 3, c8 = idx & 7;                 // 8 threads per p-row
    unsigned rr[8];
    float part = 0.f;
#pragma unroll
    for (int j = 0; j < 8; ++j) {
      unsigned u = __float_as_uint(tile[(c8 * 8 + j) * 65 + pl]);
      rr[j] = (u + 0x7fffu + ((u >> 16) & 1u)) >> 16;        // RNE to bf16
      float fr = __uint_as_float(rr[j] << 16);               // square ROUNDED value
      part += fr * fr;
    }
    uint4 o = { rr[0] | (rr[1] << 16), rr[2] | (rr[3] << 16),
                rr[4] | (rr[5] << 16), rr[6] | (rr[7] << 16) };
    *(uint4*)&X[((size_t)(p0 + pl) * NROW + i) * NCH + c0 + c8 * 8] = o;
    // row-reduce over the 8 threads sharing pl (t bits 0..2)
    part += __shfl_xor(part, 1, 64);
    part += __shfl_xor(part, 2, 64);
    part += __shfl_xor(part, 4, 64);
    if (c8 == 0)
      SQP[(size_t)cb * (NPOS * NROW) + (size_t)(p0 + pl) * NROW + i] = part;
  }
}

// ---------------------------------------------------------------------------
// Kernel 2: fused Gram + RBF-sum epilogue, upper-triangle tiles only.
// LDS exactly 32768 B (As+Bs only) -> LDS cap 5 blocks/CU. launch_bounds
// (256,4): r8-proven VGPR=64 (NO spill; (256,5) forced VGPR=48 and spilled
// the 64-reg accumulator -> 202MB scratch FETCH, r9 disaster).
// SQ staged into dead As space AFTER the K-loop; per-WAVE partials to global.
// grid: 256 pos * 10 tiles(128x128) = 2560 blocks, 4 waves (2x2).
// ---------------------------------------------------------------------------
__device__ __forceinline__ int swz(int row, int byteoff) {
  return row * 128 + (byteoff ^ ((row & 7) << 4));
}

__global__ __launch_bounds__(256, 4) void k_mmd(const unsigned short* __restrict__ X,
                                                const float* __restrict__ SQP,
                                                float* __restrict__ part) {
  __shared__ unsigned short As[128 * 64];   // 16384 B
  __shared__ unsigned short Bs[128 * 64];   // 16384 B   -> total exactly 32768

  int bid = blockIdx.x;
  int bx = (bid & 7) * 320 + (bid >> 3);   // XCD swizzle (bijective: 2560 = 8*320)
  int p = bx / 10;
  int tileid = bx - p * 10;
  int it, jt;
  if (tileid < 4)      { it = 0; jt = tileid; }
  else if (tileid < 7) { it = 1; jt = tileid - 3; }
  else if (tileid < 9) { it = 2; jt = tileid - 5; }
  else                 { it = 3; jt = 3; }
  int i0 = it * 128, j0 = jt * 128;
  int t = threadIdx.x;
  int lane = t & 63, w = t >> 6;
  int wr = w >> 1, wc = w & 1;
  int l15 = lane & 15, lk = lane >> 4;
  bool diag = (it == jt);
  bool skipw = diag && (w == 2);           // mirror of wave (0,1)
  bool areuse = diag && (wr == wc);        // Gram: B-frags == A-frags

  const unsigned short* Xp = X + (size_t)p * (NROW * NCH);
  const char* XA = (const char*)Xp + (size_t)i0 * 512;   // 512 B per row
  const char* XB = (const char*)Xp + (size_t)j0 * 512;

  f32x4 zero = {0.f, 0.f, 0.f, 0.f};
  f32x4 acc[4][4];
#pragma unroll
  for (int m = 0; m < 4; ++m)
#pragma unroll
    for (int n = 0; n < 4; ++n) acc[m][n] = zero;

  // per-lane constant source swizzle: row&7 == lane>>3 for every issued chunk
  int lrow = lane >> 3;
  int coff = ((lane & 7) ^ lrow) * 16;

  for (int kk = 0; kk < 4; ++kk) {
#pragma unroll
    for (int s = 0; s < 4; ++s) {
      int rbase = w * 32 + s * 8;          // wave-uniform
      const char* ga = XA + (size_t)(rbase + lrow) * 512 + kk * 128 + coff;
      const char* gb = XB + (size_t)(rbase + lrow) * 512 + kk * 128 + coff;
      __builtin_amdgcn_global_load_lds(
          (const __attribute__((address_space(1))) void*)ga,
          (__attribute__((address_space(3))) void*)((char*)As + rbase * 128), 16, 0, 0);
      __builtin_amdgcn_global_load_lds(
          (const __attribute__((address_space(1))) void*)gb,
          (__attribute__((address_space(3))) void*)((char*)Bs + rbase * 128), 16, 0, 0);
    }
    __syncthreads();                       // drains vmcnt(0): staged data visible
    if (!skipw) {
#pragma unroll
      for (int ks = 0; ks < 2; ++ks) {
        bf16x8 a[4], b[4];
#pragma unroll
        for (int m = 0; m < 4; ++m)
          a[m] = *(const bf16x8*)((const char*)As + swz(wr * 64 + m * 16 + l15, ks * 64 + lk * 16));
        if (areuse) {
#pragma unroll
          for (int n = 0; n < 4; ++n) b[n] = a[n];
        } else {
#pragma unroll
          for (int n = 0; n < 4; ++n)
            b[n] = *(const bf16x8*)((const char*)Bs + swz(wc * 64 + n * 16 + l15, ks * 64 + lk * 16));
        }
#pragma unroll
        for (int m = 0; m < 4; ++m)
#pragma unroll
          for (int n = 0; n < 4; ++n)
            acc[m][n] = __builtin_amdgcn_mfma_f32_16x16x32_bf16(a[m], b[n], acc[m][n], 0, 0, 0);
      }
    }
    __syncthreads();
  }

  // K-loop done; As is dead -> stage SQ sums there (256 floats)
  float* SQsh = (float*)As;
  if (t < 128) {
    size_t q = (size_t)p * NROW + i0 + t;
    SQsh[t] = SQP[q] + SQP[q + 131072] + SQP[q + 262144] + SQP[q + 393216];
  } else if (t < 256) {
    size_t q = (size_t)p * NROW + j0 + (t - 128);
    SQsh[t] = SQP[q] + SQP[q + 131072] + SQP[q + 262144] + SQP[q + 393216];
  }
  __syncthreads();

  // epilogue: D = sqi + sqj - 2c ; K = sum_b exp(-D/b) via 1 exp2 + squarings
  float lsum = 0.f;
  if (!skipw) {
    const float c80 = 0.01803368801f;  // log2(e)/80
    float sqi[16], sqj[4];
#pragma unroll
    for (int m = 0; m < 4; ++m)
#pragma unroll
      for (int r = 0; r < 4; ++r) sqi[m * 4 + r] = SQsh[wr * 64 + m * 16 + lk * 4 + r];
#pragma unroll
    for (int n = 0; n < 4; ++n) sqj[n] = SQsh[128 + wc * 64 + n * 16 + l15];

    bool sdiag = diag && (wr == wc);
#pragma unroll
    for (int m = 0; m < 4; ++m) {
#pragma unroll
      for (int n = 0; n < 4; ++n) {
#pragma unroll
        for (int r = 0; r < 4; ++r) {
          float cv = acc[m][n][r];
          float D = sqi[m * 4 + r] + sqj[n] - 2.f * cv;
          float e80 = exp2f(-c80 * D);     // exp(-D/80)
          float e40 = e80 * e80;
          float e20 = e40 * e40;
          float e10 = e20 * e20;
          float e5  = e10 * e10;
          float e2  = e5 * e5 * e10;       // exp(-D/2)
          float K = (e80 + e40) + (e20 + e10) + (e5 + e2);
          if (sdiag && m == n) {
            if (lk * 4 + r == l15) K = 6.0f;   // exact diagonal: D==0 -> K=6
          }
          lsum += K;
        }
      }
    }
    if (diag && w == 1) lsum *= 2.0f;      // stands in for skipped mirror wave
  }
  // per-wave partial reduce; ALL waves write their slot (skipw writes 0)
#pragma unroll
  for (int off = 32; off; off >>= 1) lsum += __shfl_down(lsum, off, 64);
  if (lane == 0) {
    float sgn = ((it < 2) == (jt < 2)) ? 1.0f : -1.0f;
    float tw  = diag ? 1.0f : 2.0f;        // off-diag tiles count twice (symmetry)
    part[bx * 4 + w] = sgn * tw * lsum;
  }
}

// ---------------------------------------------------------------------------
// Kernel 3: deterministic final reduce of 10240 per-wave partials -> mean
// ---------------------------------------------------------------------------
__global__ __launch_bounds__(256) void k_reduce(const float* __restrict__ part,
                                                float* __restrict__ out) {
  __shared__ float wsum[4];
  int t = threadIdx.x;
  float s = 0.f;
#pragma unroll
  for (int i = 0; i < 40; ++i) s += part[i * 256 + t];
#pragma unroll
  for (int off = 32; off; off >>= 1) s += __shfl_down(s, off, 64);
  int lane = t & 63, w = t >> 6;
  if (lane == 0) wsum[w] = s;
  __syncthreads();
  if (t == 0) out[0] = (wsum[0] + wsum[1] + wsum[2] + wsum[3]) * (1.0f / 16777216.0f);
}

extern "C" void kernel_launch(void* const* d_in, const int* in_sizes, int n_in,
                              void* d_out, int out_size, void* d_ws, size_t ws_size,
                              hipStream_t stream) {
  (void)in_sizes; (void)n_in; (void)out_size; (void)ws_size;
  const float* src = (const float*)d_in[0];
  const float* tgt = (const float*)d_in[1];
  char* ws = (char*)d_ws;
  unsigned short* X = (unsigned short*)ws;                    // 67,108,864 B
  float* SQP  = (float*)(ws + 67108864);                      //  2,097,152 B (4 partials)
  float* PART = (float*)(ws + 67108864 + 2097152);            //     40,960 B

  hipLaunchKernelGGL(k_repack, dim3(8192), dim3(256), 0, stream, src, tgt, X, SQP);
  hipLaunchKernelGGL(k_mmd,    dim3(2560), dim3(256), 0, stream, X, SQP, PART);
  hipLaunchKernelGGL(k_reduce, dim3(1),    dim3(256), 0, stream, PART, (float*)d_out);
}